// Round 2
// baseline (170.750 us; speedup 1.0000x reference)
//
#include <hip/hip_runtime.h>
#include <cstdint>
#include <cstddef>

// B=32 batch, K=4096 complex input pixels, N=4096 complex outputs.
// out[b,n] = sum_k (e_in[b,k]*ts[k]) * w[k,n]   (complex)
// Real-GEMM formulation, K'=8192 interleaved (re,im):
//   A[b][2k]=m_re, A[b][2k+1]=m_im
//   B_re[2k][n]=w_re, B_re[2k+1][n]=-w_im  -> out_re
//   B_im[2k][n]=w_im, B_im[2k+1][n]= w_re  -> out_im
// OUTPUT (established R5): float32 PLANAR — [re-plane 131072][im-plane 131072].
#define KC 4096
#define NN 4096
#define NB 32
#define HALF (NB * NN)

typedef __attribute__((ext_vector_type(8))) short  bf16x8;  // 8 bf16 (4 VGPRs)
typedef __attribute__((ext_vector_type(16))) float f32x16;  // 32x32 MFMA acc

__device__ __forceinline__ unsigned short f2bf(float f) {
    union { float f; unsigned u; } v; v.f = f;
    unsigned r = v.u + 0x7fffu + ((v.u >> 16) & 1u);
    return (unsigned short)(r >> 16);
}

// ---------------------------------------------------------------------------
// Kernel 1: modulated[b,k] = e_in[b,k] * (sigmoid(amp[k]) * exp(i*phase[k]))
// bf16 pairs in MFMA-A octet order: k'=2k+(re:0/im:1), octet o=k'>>3 (=k>>2),
// slot r=k'&7; dword index = ((k>>2)*32 + b)*4 + (k&3), re lo16 / im hi16.
// ---------------------------------------------------------------------------
__global__ __launch_bounds__(256) void prep_kernel(
    const float* __restrict__ in_re, const float* __restrict__ in_im,
    const float* __restrict__ amp,   const float* __restrict__ phase,
    uint32_t* __restrict__ wsA)
{
    int tid = blockIdx.x * 256 + threadIdx.x;   // 32*4096 threads
    int b = tid >> 12;
    int k = tid & (KC - 1);
    float er = in_re[tid], ei = in_im[tid];
    float a = amp[k], p = phase[k];
    float s = 1.0f / (1.0f + __expf(-a));
    float sn = __sinf(p);
    float cs = __cosf(p);
    float tr = s * cs, ti = s * sn;
    float mr = er * tr - ei * ti;
    float mi = er * ti + ei * tr;
    uint32_t pk = (uint32_t)f2bf(mr) | ((uint32_t)f2bf(mi) << 16);
    wsA[((((k >> 2) << 5) + b) << 2) | (k & 3)] = pk;
}

// ---------------------------------------------------------------------------
// Kernel 2 (R7): split-K complex GEMM, T3+T4 structure.
// Per step (8 complex k): stage W-tile [8 k-rows x 128 n x {re,im}] = 8 KB and
// A-octets (1 KB, shared by all 4 waves) into double-buffered LDS via
// global_load_lds (3 VMEM/wave/step), raw s_barrier + counted vmcnt(3) so the
// next tile's loads stay in flight across barriers (never drain to 0 in loop).
// Compute: ds_read afrag (b128) + 8 LDS floats -> pack bR/bI -> 2 MFMA.
// LDS W layout [k(8)][n(128)] f32: bank = n&31 = l32 -> 2-way (free, m136).
// ---------------------------------------------------------------------------
__global__ __launch_bounds__(256, 4) void gemm_kernel(
    const float* __restrict__ w_re, const float* __restrict__ w_im,
    const uint32_t* __restrict__ wsA, float2* __restrict__ wsP, int steps)
{
    __shared__ float    ldsW[2][2][8][128];   // [buf][re/im][k][n]  16 KB
    __shared__ uint32_t ldsA[2][256];         // [buf][oct(2)*b(32)*4dw]  2 KB

    const int tid  = threadIdx.x;
    const int lane = tid & 63;
    const int wave = tid >> 6;
    const int h    = lane >> 5;     // K'-octet half
    const int l32  = lane & 31;     // n within wave's 32-col slice
    const int n    = blockIdx.x * 128 + wave * 32 + l32;
    const int s    = blockIdx.y;
    const int kbase = s * (steps * 8);   // complex-k base of this split

    // Staging addresses. Thread covers row8 = tid>>5 of the 8-row tile,
    // 16 B of n at nof; wave w covers rows 2w..2w+1 -> LDS dest base row 2w
    // (glds writes wave-uniform base + lane*16, linear in lane: verified
    // (l>>5)*512 + (l&31)*16 == l*16).
    const int row8 = tid >> 5;
    const int nof  = (tid & 31) << 2;
    const float* gre = w_re + (size_t)(kbase + row8) * NN + blockIdx.x * 128 + nof;
    const float* gim = w_im + (size_t)(kbase + row8) * NN + blockIdx.x * 128 + nof;
    const uint32_t* ga = wsA + (size_t)(kbase >> 2) * 128 + tid;  // 256 dw/step

    f32x16 accR = {};
    f32x16 accI = {};

    auto STAGE = [&](int t, int bb) {
        __builtin_amdgcn_global_load_lds(
            (const __attribute__((address_space(1))) void*)(gre + (size_t)t * 8 * NN),
            (__attribute__((address_space(3))) void*)(&ldsW[bb][0][2 * wave][0]),
            16, 0, 0);
        __builtin_amdgcn_global_load_lds(
            (const __attribute__((address_space(1))) void*)(gim + (size_t)t * 8 * NN),
            (__attribute__((address_space(3))) void*)(&ldsW[bb][1][2 * wave][0]),
            16, 0, 0);
        __builtin_amdgcn_global_load_lds(
            (const __attribute__((address_space(1))) void*)(ga + (size_t)t * 256),
            (__attribute__((address_space(3))) void*)(&ldsA[bb][wave * 64]),
            4, 0, 0);
    };

    auto COMPUTE = [&](int bb) {
        // A fragment: dwords (h*32 + l32)*4 .. +3 of this step's 2 octets
        bf16x8 afrag = *(const bf16x8*)&ldsA[bb][h * 128 + l32 * 4];
        const float* Lre = &ldsW[bb][0][h * 4][wave * 32 + l32];
        const float* Lim = &ldsW[bb][1][h * 4][wave * 32 + l32];
        float r0 = Lre[0], r1 = Lre[128], r2 = Lre[256], r3 = Lre[384];
        float i0 = Lim[0], i1 = Lim[128], i2 = Lim[256], i3 = Lim[384];

        bf16x8 bR, bI;
        bR[0] = (short)f2bf(r0);  bR[1] = (short)f2bf(-i0);
        bR[2] = (short)f2bf(r1);  bR[3] = (short)f2bf(-i1);
        bR[4] = (short)f2bf(r2);  bR[5] = (short)f2bf(-i2);
        bR[6] = (short)f2bf(r3);  bR[7] = (short)f2bf(-i3);
        bI[0] = (short)f2bf(i0);  bI[1] = (short)f2bf(r0);
        bI[2] = (short)f2bf(i1);  bI[3] = (short)f2bf(r1);
        bI[4] = (short)f2bf(i2);  bI[5] = (short)f2bf(r2);
        bI[6] = (short)f2bf(i3);  bI[7] = (short)f2bf(r3);

        accR = __builtin_amdgcn_mfma_f32_32x32x16_bf16(afrag, bR, accR, 0, 0, 0);
        accI = __builtin_amdgcn_mfma_f32_32x32x16_bf16(afrag, bI, accI, 0, 0, 0);
    };

    STAGE(0, 0);
    for (int t = 0; t < steps - 1; ++t) {
        STAGE(t + 1, (t + 1) & 1);
        // Wait own 3 oldest (tile t) done; tile t+1's 3 stay in flight.
        // vmcnt completes in issue order (m135), so count==3 is exact.
        asm volatile("s_waitcnt vmcnt(3)" ::: "memory");
        __builtin_amdgcn_s_barrier();
        COMPUTE(t & 1);
        __builtin_amdgcn_s_barrier();   // protect buf[(t+1)&1]^1 from next STAGE
    }
    asm volatile("s_waitcnt vmcnt(0)" ::: "memory");
    __builtin_amdgcn_s_barrier();
    COMPUTE((steps - 1) & 1);

    // C/D layout (32x32, verified m74/m101): col = lane&31 (=n),
    // row(batch) = (reg&3) + 8*(reg>>2) + 4*h
#pragma unroll
    for (int r = 0; r < 16; ++r) {
        int brow = (r & 3) + 8 * (r >> 2) + 4 * h;
        float2 v; v.x = accR[r]; v.y = accI[r];
        wsP[((size_t)s * NB + brow) * NN + n] = v;
    }
}

// ---------------------------------------------------------------------------
// Kernel 3: planar output (proven R5): out[b*4096+n]=re, out[HALF+..]=im
// float4 loads (2 complex per thread), unroll 8 for MLP.
// ---------------------------------------------------------------------------
__global__ __launch_bounds__(256) void reduce_kernel(
    const float4* __restrict__ wsP, float* __restrict__ out, int S)
{
    int tid = blockIdx.x * 256 + threadIdx.x;   // 65536 float4 = 2 complex
    float re0 = 0.f, im0 = 0.f, re1 = 0.f, im1 = 0.f;
#pragma unroll 8
    for (int s = 0; s < S; ++s) {
        float4 v = wsP[(size_t)s * (NB * NN / 2) + tid];
        re0 += v.x; im0 += v.y; re1 += v.z; im1 += v.w;
    }
    float2* o_re = (float2*)out + tid;
    float2* o_im = (float2*)(out + HALF) + tid;
    *o_re = make_float2(re0, re1);
    *o_im = make_float2(im0, im1);
}

extern "C" void kernel_launch(void* const* d_in, const int* in_sizes, int n_in,
                              void* d_out, int out_size, void* d_ws, size_t ws_size,
                              hipStream_t stream)
{
    const float* in_re  = (const float*)d_in[0];
    const float* in_im  = (const float*)d_in[1];
    const float* w_re   = (const float*)d_in[2];
    const float* w_im   = (const float*)d_in[3];
    const float* amp    = (const float*)d_in[4];
    const float* phase  = (const float*)d_in[5];

    const size_t A_BYTES = (size_t)1024 * 32 * 16;   // 512 KB bf16 A-fragments
    uint32_t* wsA = (uint32_t*)d_ws;
    float2*   wsP = (float2*)((char*)d_ws + A_BYTES);

    // S=32 -> grid 1024 blocks (4/CU, 4 waves/SIMD). Fallback halves S if the
    // 32 MB partial buffer doesn't fit the workspace.
    int S = 32;
    while (S > 1 && A_BYTES + (size_t)S * NB * NN * sizeof(float2) > ws_size) S >>= 1;
    int steps = (KC / S) / 8;

    prep_kernel<<<dim3((NB * KC) / 256), dim3(256), 0, stream>>>(
        in_re, in_im, amp, phase, wsA);

    gemm_kernel<<<dim3(NN / 128, S), dim3(256), 0, stream>>>(
        w_re, w_im, wsA, wsP, steps);

    reduce_kernel<<<dim3((NB * NN / 2) / 256), dim3(256), 0, stream>>>(
        (const float4*)wsP, (float*)d_out, S);
}

// Round 3
// 166.520 us; speedup vs baseline: 1.0254x; 1.0254x over previous
//
#include <hip/hip_runtime.h>
#include <cstdint>
#include <cstddef>

// B=32 batch, K=4096 complex input pixels, N=4096 complex outputs.
// out[b,n] = sum_k (e_in[b,k]*ts[k]) * w[k,n]   (complex)
// Real-GEMM formulation, K'=8192 interleaved (re,im):
//   A[b][2k]=m_re, A[b][2k+1]=m_im
//   B_re[2k][n]=w_re, B_re[2k+1][n]=-w_im  -> out_re
//   B_im[2k][n]=w_im, B_im[2k+1][n]= w_re  -> out_im
// OUTPUT (established R5): float32 PLANAR — [re-plane 131072][im-plane 131072].
#define KC 4096
#define NN 4096
#define NB 32
#define HALF (NB * NN)

// R8: deep pipeline. R7's 1-deep prefetch exposed ~L/2 of HBM latency per
// step -> ~1.8 TB/s (Little's law: only ~4 KB in flight/wave). NBUF=8
// buffers, DEPTH=7 tiles prefetched ahead, steady-state vmcnt(21) = 7
// tiles x 3 loads never drained in the main loop (T3/T4, m218).
#define NBUF  8
#define DEPTH 7

typedef __attribute__((ext_vector_type(8))) short  bf16x8;  // 8 bf16 (4 VGPRs)
typedef __attribute__((ext_vector_type(16))) float f32x16;  // 32x32 MFMA acc

__device__ __forceinline__ unsigned short f2bf(float f) {
    union { float f; unsigned u; } v; v.f = f;
    unsigned r = v.u + 0x7fffu + ((v.u >> 16) & 1u);
    return (unsigned short)(r >> 16);
}

// ---------------------------------------------------------------------------
// Kernel 1: modulated[b,k] = e_in[b,k] * (sigmoid(amp[k]) * exp(i*phase[k]))
// bf16 pairs in MFMA-A octet order: k'=2k+(re:0/im:1), octet o=k'>>3 (=k>>2),
// slot r=k'&7; dword index = ((k>>2)*32 + b)*4 + (k&3), re lo16 / im hi16.
// ---------------------------------------------------------------------------
__global__ __launch_bounds__(256) void prep_kernel(
    const float* __restrict__ in_re, const float* __restrict__ in_im,
    const float* __restrict__ amp,   const float* __restrict__ phase,
    uint32_t* __restrict__ wsA)
{
    int tid = blockIdx.x * 256 + threadIdx.x;   // 32*4096 threads
    int b = tid >> 12;
    int k = tid & (KC - 1);
    float er = in_re[tid], ei = in_im[tid];
    float a = amp[k], p = phase[k];
    float s = 1.0f / (1.0f + __expf(-a));
    float sn = __sinf(p);
    float cs = __cosf(p);
    float tr = s * cs, ti = s * sn;
    float mr = er * tr - ei * ti;
    float mi = er * ti + ei * tr;
    uint32_t pk = (uint32_t)f2bf(mr) | ((uint32_t)f2bf(mi) << 16);
    wsA[((((k >> 2) << 5) + b) << 2) | (k & 3)] = pk;
}

// ---------------------------------------------------------------------------
// Kernel 2 (R8): split-K complex GEMM, deep-pipelined T3+T4 structure.
// Per step (8 complex k): stage W-tile [8 k-rows x 128 n x {re,im}] = 8 KB
// and A-octets (1 KB) into 8-deep rotating LDS buffers via global_load_lds
// (3 VMEM/wave/step). Main loop holds 21 loads (7 tiles) in flight per wave
// at all times — never drains below vmcnt(21). Epilogue: one vmcnt(0) +
// barrier, then 7 barrier-free COMPUTEs (buffers are no longer rewritten).
// LDS W layout [k(8)][n(128)] f32: bank = n&31 = l32 -> 2-way (free, m136).
// ---------------------------------------------------------------------------
__global__ __launch_bounds__(256, 2) void gemm_kernel(
    const float* __restrict__ w_re, const float* __restrict__ w_im,
    const uint32_t* __restrict__ wsA, float2* __restrict__ wsP, int steps)
{
    __shared__ float    ldsW[NBUF][2][8][128];   // [buf][re/im][k][n]  64 KB
    __shared__ uint32_t ldsA[NBUF][256];         // [buf][oct(2)*b(32)*4dw] 8 KB

    const int tid  = threadIdx.x;
    const int lane = tid & 63;
    const int wave = tid >> 6;
    const int h    = lane >> 5;     // K'-octet half
    const int l32  = lane & 31;     // n within wave's 32-col slice
    const int n    = blockIdx.x * 128 + wave * 32 + l32;
    const int s    = blockIdx.y;
    const int kbase = s * (steps * 8);   // complex-k base of this split

    // Staging addresses. Thread covers row8 = tid>>5 of the 8-row tile,
    // 16 B of n at nof; wave w covers rows 2w..2w+1 -> LDS dest base row 2w
    // (glds writes wave-uniform base + lane*16, linear in lane).
    const int row8 = tid >> 5;
    const int nof  = (tid & 31) << 2;
    const float* gre = w_re + (size_t)(kbase + row8) * NN + blockIdx.x * 128 + nof;
    const float* gim = w_im + (size_t)(kbase + row8) * NN + blockIdx.x * 128 + nof;
    const uint32_t* ga = wsA + (size_t)(kbase >> 2) * 128 + tid;  // 256 dw/step

    f32x16 accR = {};
    f32x16 accI = {};

    auto STAGE = [&](int t) {
        int tt = t < steps ? t : steps - 1;   // clamp (safety if steps < DEPTH)
        int bb = t & (NBUF - 1);
        __builtin_amdgcn_global_load_lds(
            (const __attribute__((address_space(1))) void*)(gre + (size_t)tt * 8 * NN),
            (__attribute__((address_space(3))) void*)(&ldsW[bb][0][2 * wave][0]),
            16, 0, 0);
        __builtin_amdgcn_global_load_lds(
            (const __attribute__((address_space(1))) void*)(gim + (size_t)tt * 8 * NN),
            (__attribute__((address_space(3))) void*)(&ldsW[bb][1][2 * wave][0]),
            16, 0, 0);
        __builtin_amdgcn_global_load_lds(
            (const __attribute__((address_space(1))) void*)(ga + (size_t)tt * 256),
            (__attribute__((address_space(3))) void*)(&ldsA[bb][wave * 64]),
            4, 0, 0);
    };

    auto COMPUTE = [&](int t) {
        int bb = t & (NBUF - 1);
        // A fragment: dwords (h*32 + l32)*4 .. +3 of this step's 2 octets
        bf16x8 afrag = *(const bf16x8*)&ldsA[bb][h * 128 + l32 * 4];
        const float* Lre = &ldsW[bb][0][h * 4][wave * 32 + l32];
        const float* Lim = &ldsW[bb][1][h * 4][wave * 32 + l32];
        float r0 = Lre[0], r1 = Lre[128], r2 = Lre[256], r3 = Lre[384];
        float i0 = Lim[0], i1 = Lim[128], i2 = Lim[256], i3 = Lim[384];

        bf16x8 bR, bI;
        bR[0] = (short)f2bf(r0);  bR[1] = (short)f2bf(-i0);
        bR[2] = (short)f2bf(r1);  bR[3] = (short)f2bf(-i1);
        bR[4] = (short)f2bf(r2);  bR[5] = (short)f2bf(-i2);
        bR[6] = (short)f2bf(r3);  bR[7] = (short)f2bf(-i3);
        bI[0] = (short)f2bf(i0);  bI[1] = (short)f2bf(r0);
        bI[2] = (short)f2bf(i1);  bI[3] = (short)f2bf(r1);
        bI[4] = (short)f2bf(i2);  bI[5] = (short)f2bf(r2);
        bI[6] = (short)f2bf(i3);  bI[7] = (short)f2bf(r3);

        accR = __builtin_amdgcn_mfma_f32_32x32x16_bf16(afrag, bR, accR, 0, 0, 0);
        accI = __builtin_amdgcn_mfma_f32_32x32x16_bf16(afrag, bI, accI, 0, 0, 0);
    };

    // Prologue: fill DEPTH tiles (21 loads outstanding).
#pragma unroll
    for (int t = 0; t < DEPTH; ++t) STAGE(t);

    // Main loop: tile t consumed while tiles t+1..t+DEPTH (21 ops) in flight.
    // vmcnt completes oldest-first (m135), so vmcnt(21) == "tile t landed".
    // STAGE(t+DEPTH) overwrites buf[(t-1)&7], protected by iter t-1's
    // trailing barrier.
    for (int t = 0; t < steps - DEPTH; ++t) {
        STAGE(t + DEPTH);
        asm volatile("s_waitcnt vmcnt(21)" ::: "memory");
        __builtin_amdgcn_s_barrier();
        COMPUTE(t);
        __builtin_amdgcn_s_barrier();
    }

    // Epilogue: everything staged; drain once, then barrier-free computes.
    asm volatile("s_waitcnt vmcnt(0)" ::: "memory");
    __builtin_amdgcn_s_barrier();
    for (int t = steps - DEPTH; t < steps; ++t) COMPUTE(t);

    // C/D layout (32x32, verified m74/m101): col = lane&31 (=n),
    // row(batch) = (reg&3) + 8*(reg>>2) + 4*h
#pragma unroll
    for (int r = 0; r < 16; ++r) {
        int brow = (r & 3) + 8 * (r >> 2) + 4 * h;
        float2 v; v.x = accR[r]; v.y = accI[r];
        wsP[((size_t)s * NB + brow) * NN + n] = v;
    }
}

// ---------------------------------------------------------------------------
// Kernel 3: planar output (proven R5): out[b*4096+n]=re, out[HALF+..]=im
// float4 loads (2 complex per thread).
// ---------------------------------------------------------------------------
__global__ __launch_bounds__(256) void reduce_kernel(
    const float4* __restrict__ wsP, float* __restrict__ out, int S)
{
    int tid = blockIdx.x * 256 + threadIdx.x;   // 65536 float4 = 2 complex
    float re0 = 0.f, im0 = 0.f, re1 = 0.f, im1 = 0.f;
#pragma unroll 8
    for (int s = 0; s < S; ++s) {
        float4 v = wsP[(size_t)s * (NB * NN / 2) + tid];
        re0 += v.x; im0 += v.y; re1 += v.z; im1 += v.w;
    }
    float2* o_re = (float2*)out + tid;
    float2* o_im = (float2*)(out + HALF) + tid;
    *o_re = make_float2(re0, re1);
    *o_im = make_float2(im0, im1);
}

extern "C" void kernel_launch(void* const* d_in, const int* in_sizes, int n_in,
                              void* d_out, int out_size, void* d_ws, size_t ws_size,
                              hipStream_t stream)
{
    const float* in_re  = (const float*)d_in[0];
    const float* in_im  = (const float*)d_in[1];
    const float* w_re   = (const float*)d_in[2];
    const float* w_im   = (const float*)d_in[3];
    const float* amp    = (const float*)d_in[4];
    const float* phase  = (const float*)d_in[5];

    const size_t A_BYTES = (size_t)1024 * 32 * 16;   // 512 KB bf16 A-fragments
    uint32_t* wsA = (uint32_t*)d_ws;
    float2*   wsP = (float2*)((char*)d_ws + A_BYTES);

    // S=16: grid 512 (2 blocks/CU, 144 KB LDS/CU), 16 MB partials, steps=32.
    int S = 16;
    while (S > 1 && A_BYTES + (size_t)S * NB * NN * sizeof(float2) > ws_size) S >>= 1;
    int steps = (KC / S) / 8;

    prep_kernel<<<dim3((NB * KC) / 256), dim3(256), 0, stream>>>(
        in_re, in_im, amp, phase, wsA);

    gemm_kernel<<<dim3(NN / 128, S), dim3(256), 0, stream>>>(
        w_re, w_im, wsA, wsP, steps);

    reduce_kernel<<<dim3((NB * NN / 2) / 256), dim3(256), 0, stream>>>(
        (const float4*)wsP, (float*)d_out, S);
}

// Round 4
// 164.014 us; speedup vs baseline: 1.0411x; 1.0153x over previous
//
#include <hip/hip_runtime.h>
#include <cstdint>
#include <cstddef>

// B=32 batch, K=4096 complex input pixels, N=4096 complex outputs.
// out[b,n] = sum_k (e_in[b,k]*ts[k]) * w[k,n]   (complex)
// Real-GEMM formulation, K'=8192 interleaved (re,im):
//   A[b][2k]=m_re, A[b][2k+1]=m_im
//   B_re[2k][n]=w_re, B_re[2k+1][n]=-w_im  -> out_re
//   B_im[2k][n]=w_im, B_im[2k+1][n]= w_re  -> out_im
// OUTPUT (established R5): float32 PLANAR — [re-plane 131072][im-plane 131072].
#define KC 4096
#define NN 4096
#define NB 32
#define HALF (NB * NN)
#define KB 32            // complex k per big step (R9)

typedef __attribute__((ext_vector_type(8))) short  bf16x8;  // 8 bf16 (4 VGPRs)
typedef __attribute__((ext_vector_type(16))) float f32x16;  // 32x32 MFMA acc

__device__ __forceinline__ unsigned short f2bf(float f) {
    union { float f; unsigned u; } v; v.f = f;
    unsigned r = v.u + 0x7fffu + ((v.u >> 16) & 1u);
    return (unsigned short)(r >> 16);
}

// ---------------------------------------------------------------------------
// Kernel 1: modulated[b,k] = e_in[b,k] * (sigmoid(amp[k]) * exp(i*phase[k]))
// bf16 pairs in MFMA-A octet order: k'=2k+(re:0/im:1), octet o=k'>>3 (=k>>2),
// slot r=k'&7; dword index = ((k>>2)*32 + b)*4 + (k&3), re lo16 / im hi16.
// ---------------------------------------------------------------------------
__global__ __launch_bounds__(256) void prep_kernel(
    const float* __restrict__ in_re, const float* __restrict__ in_im,
    const float* __restrict__ amp,   const float* __restrict__ phase,
    uint32_t* __restrict__ wsA)
{
    int tid = blockIdx.x * 256 + threadIdx.x;   // 32*4096 threads
    int b = tid >> 12;
    int k = tid & (KC - 1);
    float er = in_re[tid], ei = in_im[tid];
    float a = amp[k], p = phase[k];
    float s = 1.0f / (1.0f + __expf(-a));
    float sn = __sinf(p);
    float cs = __cosf(p);
    float tr = s * cs, ti = s * sn;
    float mr = er * tr - ei * ti;
    float mi = er * ti + ei * tr;
    uint32_t pk = (uint32_t)f2bf(mr) | ((uint32_t)f2bf(mi) << 16);
    wsA[((((k >> 2) << 5) + b) << 2) | (k & 3)] = pk;
}

// ---------------------------------------------------------------------------
// Kernel 2 (R9): split-K complex GEMM, COARSE steps.
// R5-R8 all hit ~49-55us regardless of pipeline depth -> per-step fixed cost
// (2 barriers + latency chain per 9 KB / 2 MFMA) and 512-B row chunks were
// the suspects. R9: 512 threads (8 waves x 32 n-cols = 256-wide n-tile, so
// each staged W row is one FULL 1-KB contiguous glds), K-step 32 complex
// (68 KB staged + 8 MFMA/wave per barrier-pair), double-buffered LDS
// (136 KB, 1 block/CU), counted vmcnt(10) (next tile's 10 loads stay in
// flight across barriers), steps=8.
// LDS W layout [k(32)][n(256)] f32: read bank = l32 -> 2-way (free, m136).
// ---------------------------------------------------------------------------
__global__ __launch_bounds__(512) void gemm_kernel(
    const float* __restrict__ w_re, const float* __restrict__ w_im,
    const uint32_t* __restrict__ wsA, float2* __restrict__ wsP, int steps)
{
    __shared__ float    ldsW[2][2][KB][256];   // [buf][re/im][k][n]  128 KB
    __shared__ uint32_t ldsA[2][KB * 32];      // [buf][1024 dw]        8 KB

    const int tid  = threadIdx.x;
    const int lane = tid & 63;
    const int wave = tid >> 6;      // 0..7
    const int h    = lane >> 5;     // K'-octet half
    const int l32  = lane & 31;     // n within wave's 32-col slice
    const int n    = blockIdx.x * 256 + wave * 32 + l32;
    const int s    = blockIdx.y;
    const int kbase = s * (steps * KB);   // complex-k base of this split

    // W staging: per (wave, j=0..3) one full row (row = j*8+wave, 1 KB);
    // lane supplies bytes lane*16 of the row; LDS dest is the row base
    // (glds writes wave-uniform base + lane*16, linear).
    const float* gW_re = w_re + (size_t)kbase * NN + blockIdx.x * 256 + (lane << 2);
    const float* gW_im = w_im + (size_t)kbase * NN + blockIdx.x * 256 + (lane << 2);
    // A staging: per (wave, j=0..1) one 256-B chunk c = wave*2+j (64 dw);
    // lane supplies dword lane.
    const uint32_t* gA = wsA + (size_t)(kbase >> 2) * 128 + lane;

    f32x16 accR = {};
    f32x16 accI = {};

    auto STAGE = [&](int t, int bb) {
#pragma unroll
        for (int j = 0; j < 4; ++j) {
            int row = j * 8 + wave;
            __builtin_amdgcn_global_load_lds(
                (const __attribute__((address_space(1))) void*)(gW_re + (size_t)(t * KB + row) * NN),
                (__attribute__((address_space(3))) void*)(&ldsW[bb][0][row][0]),
                16, 0, 0);
        }
#pragma unroll
        for (int j = 0; j < 4; ++j) {
            int row = j * 8 + wave;
            __builtin_amdgcn_global_load_lds(
                (const __attribute__((address_space(1))) void*)(gW_im + (size_t)(t * KB + row) * NN),
                (__attribute__((address_space(3))) void*)(&ldsW[bb][1][row][0]),
                16, 0, 0);
        }
#pragma unroll
        for (int j = 0; j < 2; ++j) {
            int c = wave * 2 + j;
            __builtin_amdgcn_global_load_lds(
                (const __attribute__((address_space(1))) void*)(gA + (size_t)t * (KB * 32) + c * 64),
                (__attribute__((address_space(3))) void*)(&ldsA[bb][c * 64]),
                4, 0, 0);
        }
    };

    auto COMPUTE = [&](int bb) {
#pragma unroll
        for (int ss = 0; ss < 4; ++ss) {
            // A fragment: within step's 1024 dw, sub-step chunk ss*256,
            // then (h*32 + l32)*4 .. +3 (same dword math as verified R8).
            bf16x8 afrag = *(const bf16x8*)&ldsA[bb][ss * 256 + h * 128 + l32 * 4];
            const float* Lre = &ldsW[bb][0][ss * 8 + h * 4][wave * 32 + l32];
            const float* Lim = &ldsW[bb][1][ss * 8 + h * 4][wave * 32 + l32];
            float r0 = Lre[0], r1 = Lre[256], r2 = Lre[512], r3 = Lre[768];
            float i0 = Lim[0], i1 = Lim[256], i2 = Lim[512], i3 = Lim[768];

            // f2bf(-x) == f2bf(x)^0x8000 exactly (round-to-nearest-even is
            // sign-symmetric) -> 8 converts + 4 xors instead of 12 converts.
            unsigned short br0 = f2bf(r0), br1 = f2bf(r1), br2 = f2bf(r2), br3 = f2bf(r3);
            unsigned short bi0 = f2bf(i0), bi1 = f2bf(i1), bi2 = f2bf(i2), bi3 = f2bf(i3);
            bf16x8 bR, bI;
            bR[0] = (short)br0;  bR[1] = (short)(bi0 ^ 0x8000);
            bR[2] = (short)br1;  bR[3] = (short)(bi1 ^ 0x8000);
            bR[4] = (short)br2;  bR[5] = (short)(bi2 ^ 0x8000);
            bR[6] = (short)br3;  bR[7] = (short)(bi3 ^ 0x8000);
            bI[0] = (short)bi0;  bI[1] = (short)br0;
            bI[2] = (short)bi1;  bI[3] = (short)br1;
            bI[4] = (short)bi2;  bI[5] = (short)br2;
            bI[6] = (short)bi3;  bI[7] = (short)br3;

            accR = __builtin_amdgcn_mfma_f32_32x32x16_bf16(afrag, bR, accR, 0, 0, 0);
            accI = __builtin_amdgcn_mfma_f32_32x32x16_bf16(afrag, bI, accI, 0, 0, 0);
        }
    };

    STAGE(0, 0);
    for (int t = 0; t < steps - 1; ++t) {
        STAGE(t + 1, (t + 1) & 1);
        // Wait own 10 oldest (tile t) done; tile t+1's 10 stay in flight.
        // vmcnt completes oldest-first (m135), so count==10 is exact.
        asm volatile("s_waitcnt vmcnt(10)" ::: "memory");
        __builtin_amdgcn_s_barrier();
        COMPUTE(t & 1);
        __builtin_amdgcn_s_barrier();   // protect buf being staged next iter
    }
    asm volatile("s_waitcnt vmcnt(0)" ::: "memory");
    __builtin_amdgcn_s_barrier();
    COMPUTE((steps - 1) & 1);

    // C/D layout (32x32, verified m74/m101): col = lane&31 (=n),
    // row(batch) = (reg&3) + 8*(reg>>2) + 4*h
#pragma unroll
    for (int r = 0; r < 16; ++r) {
        int brow = (r & 3) + 8 * (r >> 2) + 4 * h;
        float2 v; v.x = accR[r]; v.y = accI[r];
        wsP[((size_t)s * NB + brow) * NN + n] = v;
    }
}

// ---------------------------------------------------------------------------
// Kernel 3: planar output (proven R5): out[b*4096+n]=re, out[HALF+..]=im
// float4 loads (2 complex per thread).
// ---------------------------------------------------------------------------
__global__ __launch_bounds__(256) void reduce_kernel(
    const float4* __restrict__ wsP, float* __restrict__ out, int S)
{
    int tid = blockIdx.x * 256 + threadIdx.x;   // 65536 float4 = 2 complex
    float re0 = 0.f, im0 = 0.f, re1 = 0.f, im1 = 0.f;
#pragma unroll 8
    for (int s = 0; s < S; ++s) {
        float4 v = wsP[(size_t)s * (NB * NN / 2) + tid];
        re0 += v.x; im0 += v.y; re1 += v.z; im1 += v.w;
    }
    float2* o_re = (float2*)out + tid;
    float2* o_im = (float2*)(out + HALF) + tid;
    *o_re = make_float2(re0, re1);
    *o_im = make_float2(im0, im1);
}

extern "C" void kernel_launch(void* const* d_in, const int* in_sizes, int n_in,
                              void* d_out, int out_size, void* d_ws, size_t ws_size,
                              hipStream_t stream)
{
    const float* in_re  = (const float*)d_in[0];
    const float* in_im  = (const float*)d_in[1];
    const float* w_re   = (const float*)d_in[2];
    const float* w_im   = (const float*)d_in[3];
    const float* amp    = (const float*)d_in[4];
    const float* phase  = (const float*)d_in[5];

    const size_t A_BYTES = (size_t)1024 * 32 * 16;   // 512 KB bf16 A-fragments
    uint32_t* wsA = (uint32_t*)d_ws;
    float2*   wsP = (float2*)((char*)d_ws + A_BYTES);

    // S=16: grid (16,16)=256 blocks of 512 thr, 1 block/CU (136 KB LDS),
    // steps=8 coarse K-steps of 32 complex k each.
    int S = 16;
    while (S > 1 && A_BYTES + (size_t)S * NB * NN * sizeof(float2) > ws_size) S >>= 1;
    int steps = (KC / S) / KB;

    prep_kernel<<<dim3((NB * KC) / 256), dim3(256), 0, stream>>>(
        in_re, in_im, amp, phase, wsA);

    gemm_kernel<<<dim3(NN / 256, S), dim3(512), 0, stream>>>(
        w_re, w_im, wsA, wsP, steps);

    reduce_kernel<<<dim3((NB * NN / 2) / 256), dim3(256), 0, stream>>>(
        (const float4*)wsP, (float*)d_out, S);
}